// Round 1
// baseline (310.688 us; speedup 1.0000x reference)
//
#include <hip/hip_runtime.h>

typedef unsigned short u16;
typedef unsigned int   u32;
typedef __attribute__((ext_vector_type(8))) short bf16x8;   // 8 bf16 = 4 VGPRs
typedef __attribute__((ext_vector_type(4))) float f32x4;
typedef __attribute__((ext_vector_type(4))) unsigned short us4;

__device__ __forceinline__ u16 f2bf(float f) {
    union { float f; u32 u; } v; v.f = f;
    u32 u = v.u;
    return (u16)((u + 0x7fffu + ((u >> 16) & 1u)) >> 16);   // RNE
}

__device__ __forceinline__ void gload_lds16(const void* g, void* l) {
    // LDS dest = wave-uniform base + lane*16 (HW behavior)
    __builtin_amdgcn_global_load_lds((const __attribute__((address_space(1))) u32*)g,
                                     (__attribute__((address_space(3))) u32*)l,
                                     16, 0, 0);
}

// ---------------------------------------------------------------------------
// bf16 GEMM, C = alpha * A * B^T (+ bias), A: MxK (lda), B: NxK (ldb).
// 128x128 tile, BK=32, 256 threads = 4 waves in 2x2, each wave 64x64 via
// 4x4 grid of 16x16x32 MFMA. m97 recipe: global_load_lds width=16 staging.
// ---------------------------------------------------------------------------
template<bool OUT_BF16, bool ADD_BIAS>
__global__ __launch_bounds__(256)
void gemm_bt(const u16* __restrict__ A, int lda, size_t strA,
             const u16* __restrict__ B, int ldb, size_t strB,
             void* __restrict__ Cv, int ldc, size_t strC,
             const float* __restrict__ bias, int K, float alpha)
{
    __shared__ __align__(16) u16 As[128 * 32];
    __shared__ __align__(16) u16 Bs[128 * 32];

    const int tid  = threadIdx.x;
    const int w    = tid >> 6;
    const int lane = tid & 63;
    const int wm   = w >> 1, wn = w & 1;
    const int m0   = blockIdx.y * 128, n0 = blockIdx.x * 128;
    const int fm   = lane & 15, fq = lane >> 4;

    A += (size_t)blockIdx.z * strA;
    B += (size_t)blockIdx.z * strB;

    f32x4 acc[4][4] = {};

    for (int k0 = 0; k0 < K; k0 += 32) {
        // stage A(128x32) and B(128x32) bf16 tiles: 512 chunks of 16B each
#pragma unroll
        for (int h = 0; h < 2; ++h) {
            const int cb = h * 256 + w * 64;     // wave-uniform chunk base
            const int c  = cb + lane;            // this lane's chunk
            gload_lds16(A + (size_t)(m0 + (c >> 2)) * lda + (k0 + (c & 3) * 8),
                        (char*)As + cb * 16);
            gload_lds16(B + (size_t)(n0 + (c >> 2)) * ldb + (k0 + (c & 3) * 8),
                        (char*)Bs + cb * 16);
        }
        __syncthreads();

        bf16x8 af[4], bv[4];
#pragma unroll
        for (int i = 0; i < 4; ++i)
            af[i] = *(const bf16x8*)(As + (wm * 64 + i * 16 + fm) * 32 + fq * 8);
#pragma unroll
        for (int j = 0; j < 4; ++j)
            bv[j] = *(const bf16x8*)(Bs + (wn * 64 + j * 16 + fm) * 32 + fq * 8);
#pragma unroll
        for (int i = 0; i < 4; ++i)
#pragma unroll
            for (int j = 0; j < 4; ++j)
                acc[i][j] = __builtin_amdgcn_mfma_f32_16x16x32_bf16(af[i], bv[j], acc[i][j], 0, 0, 0);
        __syncthreads();
    }

    // epilogue: C/D layout col=lane&15, row=(lane>>4)*4+reg
    float bval[4];
    if (ADD_BIAS) {
#pragma unroll
        for (int j = 0; j < 4; ++j) bval[j] = bias[n0 + wn * 64 + j * 16 + fm];
    }
#pragma unroll
    for (int i = 0; i < 4; ++i) {
        const int row = m0 + wm * 64 + i * 16 + fq * 4;
#pragma unroll
        for (int j = 0; j < 4; ++j) {
            const int col = n0 + wn * 64 + j * 16 + fm;
#pragma unroll
            for (int r = 0; r < 4; ++r) {
                float v = acc[i][j][r] * alpha;
                if (ADD_BIAS) v += bval[j];
                if (OUT_BF16)
                    ((u16*)Cv)[(size_t)blockIdx.z * strC + (size_t)(row + r) * ldc + col] = f2bf(v);
                else
                    ((float*)Cv)[(size_t)blockIdx.z * strC + (size_t)(row + r) * ldc + col] = v;
            }
        }
    }
}

// X fp32 -> bf16, flat
__global__ __launch_bounds__(256)
void convert_x(const float* __restrict__ X, u16* __restrict__ Xb, int n4)
{
    int i = blockIdx.x * blockDim.x + threadIdx.x;
    if (i < n4) {
        float4 v = ((const float4*)X)[i];
        us4 o = { f2bf(v.x), f2bf(v.y), f2bf(v.z), f2bf(v.w) };
        ((us4*)Xb)[i] = o;
    }
}

// W (1024 x 3072 fp32) -> Wt (3072 x 1024 bf16)
__global__ __launch_bounds__(256)
void transpose_w(const float* __restrict__ W, u16* __restrict__ Wt)
{
    __shared__ u16 t[64][65];
    const int k0 = blockIdx.x * 64, n0 = blockIdx.y * 64;
    const int tx = threadIdx.x, ty = threadIdx.y;
#pragma unroll
    for (int i = 0; i < 64; i += 4)
        t[ty + i][tx] = f2bf(W[(size_t)(k0 + ty + i) * 3072 + n0 + tx]);
    __syncthreads();
#pragma unroll
    for (int i = 0; i < 64; i += 4)
        Wt[(size_t)(n0 + ty + i) * 1024 + k0 + tx] = t[tx][ty + i];
}

// V slice of QKV (per batch 2048 x 1024, bf16, row stride 3072, col off 2048)
//   -> Vt[b] (1024 x 2048 bf16)
__global__ __launch_bounds__(256)
void transpose_v(const u16* __restrict__ QKV, u16* __restrict__ Vt)
{
    __shared__ u16 t[64][65];
    const int b  = blockIdx.z;
    const int d0 = blockIdx.x * 64, s0 = blockIdx.y * 64;
    const int tx = threadIdx.x, ty = threadIdx.y;
    const u16* src = QKV + (size_t)(b * 2048 + s0) * 3072 + 2048 + d0;
#pragma unroll
    for (int i = 0; i < 64; i += 4)
        t[ty + i][tx] = src[(size_t)(ty + i) * 3072 + tx];
    __syncthreads();
    u16* dst = Vt + (size_t)b * 1024 * 2048 + (size_t)d0 * 2048 + s0;
#pragma unroll
    for (int i = 0; i < 64; i += 4)
        dst[(size_t)(ty + i) * 2048 + tx] = t[tx][ty + i];
}

// Row softmax over 2048 fp32 logits (scale already applied by GEMM alpha);
// writes bf16 P in-place into the same buffer (row stride 4096 u16).
__global__ __launch_bounds__(256)
void softmax_rows(float* __restrict__ S)
{
    __shared__ float redm[4], reds[4];
    const size_t row = blockIdx.x;
    float* sr = S + row * 2048;
    const int t = threadIdx.x;

    float4 a = ((const float4*)sr)[t];
    float4 b = ((const float4*)sr)[t + 256];

    float mx = fmaxf(fmaxf(fmaxf(a.x, a.y), fmaxf(a.z, a.w)),
                     fmaxf(fmaxf(b.x, b.y), fmaxf(b.z, b.w)));
#pragma unroll
    for (int o = 32; o; o >>= 1) mx = fmaxf(mx, __shfl_xor(mx, o));
    if ((t & 63) == 0) redm[t >> 6] = mx;
    __syncthreads();
    mx = fmaxf(fmaxf(redm[0], redm[1]), fmaxf(redm[2], redm[3]));

    float e[8];
    e[0] = __expf(a.x - mx); e[1] = __expf(a.y - mx);
    e[2] = __expf(a.z - mx); e[3] = __expf(a.w - mx);
    e[4] = __expf(b.x - mx); e[5] = __expf(b.y - mx);
    e[6] = __expf(b.z - mx); e[7] = __expf(b.w - mx);
    float s = ((e[0] + e[1]) + (e[2] + e[3])) + ((e[4] + e[5]) + (e[6] + e[7]));
#pragma unroll
    for (int o = 32; o; o >>= 1) s += __shfl_xor(s, o);
    if ((t & 63) == 0) reds[t >> 6] = s;
    __syncthreads();
    s = reds[0] + reds[1] + reds[2] + reds[3];
    const float inv = 1.0f / s;

    u16* pr = (u16*)sr;   // safe: all reads happened before the barriers above
    us4 o1 = { f2bf(e[0] * inv), f2bf(e[1] * inv), f2bf(e[2] * inv), f2bf(e[3] * inv) };
    us4 o2 = { f2bf(e[4] * inv), f2bf(e[5] * inv), f2bf(e[6] * inv), f2bf(e[7] * inv) };
    ((us4*)pr)[t]       = o1;
    ((us4*)pr)[t + 256] = o2;
}

extern "C" void kernel_launch(void* const* d_in, const int* in_sizes, int n_in,
                              void* d_out, int out_size, void* d_ws, size_t ws_size,
                              hipStream_t stream)
{
    const float* X    = (const float*)d_in[0];   // (4,2048,1024)
    const float* W    = (const float*)d_in[1];   // (1024,3072)
    const float* bias = (const float*)d_in[2];   // (3072,)
    float* out = (float*)d_out;                  // (4,2048,1024) fp32
    char* ws = (char*)d_ws;

    // ws layout (total 128 MiB):
    //   [0,            50331648)  QKV  bf16 (8192 x 3072)
    //   [50331648,     67108864)  Vt   bf16 (4 x 1024 x 2048)
    //   [67108864,    134217728)  S    fp32 (4 x 2048 x 2048), P bf16 in-place
    //   Xb/Wt alias the S region (dead before S is written):
    //   [67108864,     83886080)  Xb   bf16 (8192 x 1024)
    //   [83886080,     90177536)  Wt   bf16 (3072 x 1024)
    u16*   QKV = (u16*)ws;
    u16*   Vt  = (u16*)(ws + 50331648);
    float* S   = (float*)(ws + 67108864);
    u16*   Xb  = (u16*)(ws + 67108864);
    u16*   Wt  = (u16*)(ws + 83886080);

    // 1) fp32 -> bf16 conversions
    convert_x<<<8192, 256, 0, stream>>>(X, Xb, 8192 * 1024 / 4);
    transpose_w<<<dim3(16, 48), dim3(64, 4), 0, stream>>>(W, Wt);

    // 2) QKV = Xb @ Wt^T + b  -> bf16 (M=8192, N=3072, K=1024)
    gemm_bt<true, true><<<dim3(24, 64, 1), 256, 0, stream>>>(
        Xb, 1024, 0, Wt, 1024, 0, QKV, 3072, 0, bias, 1024, 1.0f);

    // 3) Vt[b] = V[b]^T
    transpose_v<<<dim3(16, 32, 4), dim3(64, 4), 0, stream>>>(QKV, Vt);

    // 4) S[b] = (1/32) * Q[b] @ K[b]^T  (M=N=2048, K=1024), fp32 out
    gemm_bt<false, false><<<dim3(16, 16, 4), 256, 0, stream>>>(
        QKV,        3072, (size_t)2048 * 3072,
        QKV + 1024, 3072, (size_t)2048 * 3072,
        S,          2048, (size_t)2048 * 2048,
        nullptr, 1024, 0.03125f);

    // 5) row softmax, bf16 P written in-place (row stride 4096 u16)
    softmax_rows<<<8192, 256, 0, stream>>>(S);

    // 6) out[b] = P[b] @ Vt[b]^T  (M=2048, N=1024, K=2048), fp32 out
    gemm_bt<false, false><<<dim3(8, 16, 4), 256, 0, stream>>>(
        (const u16*)S, 4096, (size_t)2048 * 4096,
        Vt,            2048, (size_t)1024 * 2048,
        out,           1024, (size_t)2048 * 1024,
        nullptr, 2048, 1.0f);
}

// Round 2
// 287.945 us; speedup vs baseline: 1.0790x; 1.0790x over previous
//
#include <hip/hip_runtime.h>

typedef unsigned short u16;
typedef unsigned int   u32;
typedef __attribute__((ext_vector_type(8)))  short bf16x8;   // 8 bf16 = 4 VGPRs
typedef __attribute__((ext_vector_type(16))) float f32x16;
typedef __attribute__((ext_vector_type(4)))  unsigned short us4;

__device__ __forceinline__ u16 f2bf(float f) {
    union { float f; u32 u; } v; v.f = f;
    u32 u = v.u;
    return (u16)((u + 0x7fffu + ((u >> 16) & 1u)) >> 16);   // RNE
}
__device__ __forceinline__ float bf2f_lo(u32 p) {
    union { u32 u; float f; } t; t.u = p << 16; return t.f;
}
__device__ __forceinline__ float bf2f_hi(u32 p) {
    union { u32 u; float f; } t; t.u = p & 0xffff0000u; return t.f;
}

__device__ __forceinline__ void gload_lds16(const void* g, void* l) {
    // LDS dest = wave-uniform base + lane*16 (HW behavior)
    __builtin_amdgcn_global_load_lds((const __attribute__((address_space(1))) u32*)g,
                                     (__attribute__((address_space(3))) u32*)l,
                                     16, 0, 0);
}

// ---------------------------------------------------------------------------
// bf16 GEMM, C = alpha * A * B^T (+ bias), A: MxK (lda), B: NxK (ldb).
// 128x128 tile, BK=32, 256 threads = 4 waves (2x2), wave-tile 64x64 as 2x2
// of 32x32x16 MFMA. Swizzled LDS layout: logical (row r, 8-elem kchunk q)
// lives at chunk index r*4 + ((q + (r>>1)) & 3)  (16B chunks) -> fragment
// reads hit all 8 bank groups uniformly. Staging permutes GLOBAL source per
// lane (global_load_lds forces LDS offset = base + lane*16).
// ---------------------------------------------------------------------------
template<bool OUT_BF16, bool ADD_BIAS>
__global__ __launch_bounds__(256)
void gemm_bt(const u16* __restrict__ A, int lda, size_t strA,
             const u16* __restrict__ B, int ldb, size_t strB,
             void* __restrict__ Cv, int ldc, size_t strC,
             const float* __restrict__ bias, int K, float alpha)
{
    __shared__ __align__(16) u16 As[128 * 32];
    __shared__ __align__(16) u16 Bs[128 * 32];

    const int tid  = threadIdx.x;
    const int w    = tid >> 6;
    const int lane = tid & 63;
    const int wm   = w >> 1, wn = w & 1;
    const int m0   = blockIdx.y * 128, n0 = blockIdx.x * 128;
    const int l31  = lane & 31, lh = lane >> 5;

    A += (size_t)blockIdx.z * strA;
    B += (size_t)blockIdx.z * strB;

    // --- staging: decode this thread's two chunk ids -> global source offset
    size_t goffA[2], goffB[2];
#pragma unroll
    for (int h = 0; h < 2; ++h) {
        const int c = h * 256 + w * 64 + lane;          // LDS chunk index
        const int r = c >> 2;                           // row 0..127
        const int q = ((c & 3) - (r >> 1)) & 3;         // logical kchunk
        goffA[h] = (size_t)(m0 + r) * lda + q * 8;
        goffB[h] = (size_t)(n0 + r) * ldb + q * 8;
    }

    // --- fragment LDS byte offsets (loop-invariant)
    int offA[2][2], offB[2][2];                         // [i|j][kstep]
#pragma unroll
    for (int i = 0; i < 2; ++i) {
        const int ra = wm * 64 + i * 32 + l31;
        const int rb = wn * 64 + i * 32 + l31;
#pragma unroll
        for (int ks = 0; ks < 2; ++ks) {
            const int qq = ks * 2 + lh;
            offA[i][ks] = (ra * 4 + ((qq + (ra >> 1)) & 3)) * 16;
            offB[i][ks] = (rb * 4 + ((qq + (rb >> 1)) & 3)) * 16;
        }
    }

    f32x16 acc[2][2] = {};

    for (int k0 = 0; k0 < K; k0 += 32) {
        gload_lds16(A + goffA[0] + k0, (char*)As + (w * 64) * 16);
        gload_lds16(A + goffA[1] + k0, (char*)As + (256 + w * 64) * 16);
        gload_lds16(B + goffB[0] + k0, (char*)Bs + (w * 64) * 16);
        gload_lds16(B + goffB[1] + k0, (char*)Bs + (256 + w * 64) * 16);
        __syncthreads();

        bf16x8 af[2][2], bfr[2][2];
#pragma unroll
        for (int i = 0; i < 2; ++i)
#pragma unroll
            for (int ks = 0; ks < 2; ++ks) {
                af[i][ks]  = *(const bf16x8*)((const char*)As + offA[i][ks]);
                bfr[i][ks] = *(const bf16x8*)((const char*)Bs + offB[i][ks]);
            }
#pragma unroll
        for (int ks = 0; ks < 2; ++ks)
#pragma unroll
            for (int i = 0; i < 2; ++i)
#pragma unroll
                for (int j = 0; j < 2; ++j)
                    acc[i][j] = __builtin_amdgcn_mfma_f32_32x32x16_bf16(
                        af[i][ks], bfr[j][ks], acc[i][j], 0, 0, 0);
        __syncthreads();
    }

    // --- epilogue: C/D layout col=lane&31, row=(reg&3)+8*(reg>>2)+4*(lane>>5)
    float bval[2];
    if (ADD_BIAS) {
#pragma unroll
        for (int j = 0; j < 2; ++j) bval[j] = bias[n0 + wn * 64 + j * 32 + l31];
    }
#pragma unroll
    for (int i = 0; i < 2; ++i) {
        const int rowb = m0 + wm * 64 + i * 32 + 4 * lh;
#pragma unroll
        for (int j = 0; j < 2; ++j) {
            const int col = n0 + wn * 64 + j * 32 + l31;
#pragma unroll
            for (int r = 0; r < 16; ++r) {
                const int row = rowb + (r & 3) + 8 * (r >> 2);
                float v = acc[i][j][r] * alpha;
                if (ADD_BIAS) v += bval[j];
                if (OUT_BF16)
                    ((u16*)Cv)[(size_t)blockIdx.z * strC + (size_t)row * ldc + col] = f2bf(v);
                else
                    ((float*)Cv)[(size_t)blockIdx.z * strC + (size_t)row * ldc + col] = v;
            }
        }
    }
}

// X fp32 -> bf16, flat
__global__ __launch_bounds__(256)
void convert_x(const float* __restrict__ X, u16* __restrict__ Xb, int n4)
{
    int i = blockIdx.x * blockDim.x + threadIdx.x;
    if (i < n4) {
        float4 v = ((const float4*)X)[i];
        us4 o = { f2bf(v.x), f2bf(v.y), f2bf(v.z), f2bf(v.w) };
        ((us4*)Xb)[i] = o;
    }
}

// W (1024 x 3072 fp32) -> Wt (3072 x 1024 bf16)
__global__ __launch_bounds__(256)
void transpose_w(const float* __restrict__ W, u16* __restrict__ Wt)
{
    __shared__ u16 t[64][65];
    const int k0 = blockIdx.x * 64, n0 = blockIdx.y * 64;
    const int tx = threadIdx.x, ty = threadIdx.y;
#pragma unroll
    for (int i = 0; i < 64; i += 4)
        t[ty + i][tx] = f2bf(W[(size_t)(k0 + ty + i) * 3072 + n0 + tx]);
    __syncthreads();
#pragma unroll
    for (int i = 0; i < 64; i += 4)
        Wt[(size_t)(n0 + ty + i) * 1024 + k0 + tx] = t[tx][ty + i];
}

// V slice of QKV (per batch 2048 x 1024 bf16, row stride 3072, col off 2048)
//   -> Vt[b] (1024 x 2048 bf16)
__global__ __launch_bounds__(256)
void transpose_v(const u16* __restrict__ QKV, u16* __restrict__ Vt)
{
    __shared__ u16 t[64][65];
    const int b  = blockIdx.z;
    const int d0 = blockIdx.x * 64, s0 = blockIdx.y * 64;
    const int tx = threadIdx.x, ty = threadIdx.y;
    const u16* src = QKV + (size_t)(b * 2048 + s0) * 3072 + 2048 + d0;
#pragma unroll
    for (int i = 0; i < 64; i += 4)
        t[ty + i][tx] = src[(size_t)(ty + i) * 3072 + tx];
    __syncthreads();
    u16* dst = Vt + (size_t)b * 1024 * 2048 + (size_t)d0 * 2048 + s0;
#pragma unroll
    for (int i = 0; i < 64; i += 4)
        dst[(size_t)(ty + i) * 2048 + tx] = t[tx][ty + i];
}

// Row softmax over 2048 bf16 logits, in place (row stride 2048 u16).
__global__ __launch_bounds__(256)
void softmax_rows(u16* __restrict__ S)
{
    __shared__ float redm[4], reds[4];
    u16* sr = S + (size_t)blockIdx.x * 2048;
    const int t = threadIdx.x;

    uint4 raw = ((const uint4*)sr)[t];                  // 8 bf16
    float x[8];
    x[0] = bf2f_lo(raw.x); x[1] = bf2f_hi(raw.x);
    x[2] = bf2f_lo(raw.y); x[3] = bf2f_hi(raw.y);
    x[4] = bf2f_lo(raw.z); x[5] = bf2f_hi(raw.z);
    x[6] = bf2f_lo(raw.w); x[7] = bf2f_hi(raw.w);

    float mx = fmaxf(fmaxf(fmaxf(x[0], x[1]), fmaxf(x[2], x[3])),
                     fmaxf(fmaxf(x[4], x[5]), fmaxf(x[6], x[7])));
#pragma unroll
    for (int o = 32; o; o >>= 1) mx = fmaxf(mx, __shfl_xor(mx, o));
    if ((t & 63) == 0) redm[t >> 6] = mx;
    __syncthreads();
    mx = fmaxf(fmaxf(redm[0], redm[1]), fmaxf(redm[2], redm[3]));

    float e[8], s = 0.f;
#pragma unroll
    for (int k = 0; k < 8; ++k) { e[k] = __expf(x[k] - mx); s += e[k]; }
#pragma unroll
    for (int o = 32; o; o >>= 1) s += __shfl_xor(s, o);
    if ((t & 63) == 0) reds[t >> 6] = s;
    __syncthreads();
    s = reds[0] + reds[1] + reds[2] + reds[3];
    const float inv = 1.0f / s;

    uint4 o4;
    o4.x = (u32)f2bf(e[0] * inv) | ((u32)f2bf(e[1] * inv) << 16);
    o4.y = (u32)f2bf(e[2] * inv) | ((u32)f2bf(e[3] * inv) << 16);
    o4.z = (u32)f2bf(e[4] * inv) | ((u32)f2bf(e[5] * inv) << 16);
    o4.w = (u32)f2bf(e[6] * inv) | ((u32)f2bf(e[7] * inv) << 16);
    ((uint4*)sr)[t] = o4;   // safe: all reads of this row happened pre-barrier
}

extern "C" void kernel_launch(void* const* d_in, const int* in_sizes, int n_in,
                              void* d_out, int out_size, void* d_ws, size_t ws_size,
                              hipStream_t stream)
{
    const float* X    = (const float*)d_in[0];   // (4,2048,1024)
    const float* W    = (const float*)d_in[1];   // (1024,3072)
    const float* bias = (const float*)d_in[2];   // (3072,)
    float* out = (float*)d_out;                  // (4,2048,1024) fp32
    char* ws = (char*)d_ws;

    // ws layout:
    //   [0,         50331648)  QKV bf16 (8192 x 3072)
    //   [50331648,  67108864)  Vt  bf16 (4 x 1024 x 2048)
    //   [67108864, 100663296)  S/P bf16 (4 x 2048 x 2048), softmax in place
    //   Xb/Wt alias the S region (dead before S is written):
    //   [67108864,  83886080)  Xb  bf16 (8192 x 1024)
    //   [83886080,  90177536)  Wt  bf16 (3072 x 1024)
    u16* QKV = (u16*)ws;
    u16* Vt  = (u16*)(ws + 50331648);
    u16* S   = (u16*)(ws + 67108864);
    u16* Xb  = (u16*)(ws + 67108864);
    u16* Wt  = (u16*)(ws + 83886080);

    // 1) fp32 -> bf16 conversions
    convert_x<<<8192, 256, 0, stream>>>(X, Xb, 8192 * 1024 / 4);
    transpose_w<<<dim3(16, 48), dim3(64, 4), 0, stream>>>(W, Wt);

    // 2) QKV = Xb @ Wt^T + b  -> bf16 (M=8192, N=3072, K=1024)
    gemm_bt<true, true><<<dim3(24, 64, 1), 256, 0, stream>>>(
        Xb, 1024, 0, Wt, 1024, 0, QKV, 3072, 0, bias, 1024, 1.0f);

    // 3) Vt[b] = V[b]^T
    transpose_v<<<dim3(16, 32, 4), dim3(64, 4), 0, stream>>>(QKV, Vt);

    // 4) S[b] = (1/32) * Q[b] @ K[b]^T  -> bf16 logits (M=N=2048, K=1024)
    gemm_bt<true, false><<<dim3(16, 16, 4), 256, 0, stream>>>(
        QKV,        3072, (size_t)2048 * 3072,
        QKV + 1024, 3072, (size_t)2048 * 3072,
        S,          2048, (size_t)2048 * 2048,
        nullptr, 1024, 0.03125f);

    // 5) row softmax in place (bf16 -> bf16 P)
    softmax_rows<<<8192, 256, 0, stream>>>(S);

    // 6) out[b] = P[b] @ Vt[b]^T  (M=2048, N=1024, K=2048), fp32 out
    gemm_bt<false, false><<<dim3(8, 16, 4), 256, 0, stream>>>(
        S,  2048, (size_t)2048 * 2048,
        Vt, 2048, (size_t)1024 * 2048,
        out, 1024, (size_t)2048 * 1024,
        nullptr, 2048, 1.0f);
}

// Round 3
// 287.022 us; speedup vs baseline: 1.0825x; 1.0032x over previous
//
#include <hip/hip_runtime.h>

typedef unsigned short u16;
typedef unsigned int   u32;
typedef __attribute__((ext_vector_type(8)))  short bf16x8;   // 8 bf16 = 4 VGPRs
typedef __attribute__((ext_vector_type(16))) float f32x16;
typedef __attribute__((ext_vector_type(4)))  unsigned short us4;

__device__ __forceinline__ u16 f2bf(float f) {
    union { float f; u32 u; } v; v.f = f;
    u32 u = v.u;
    return (u16)((u + 0x7fffu + ((u >> 16) & 1u)) >> 16);   // RNE
}
__device__ __forceinline__ float bf2f_lo(u32 p) {
    union { u32 u; float f; } t; t.u = p << 16; return t.f;
}
__device__ __forceinline__ float bf2f_hi(u32 p) {
    union { u32 u; float f; } t; t.u = p & 0xffff0000u; return t.f;
}

__device__ __forceinline__ void gload_lds16(const void* g, void* l) {
    // LDS dest = wave-uniform base + lane*16 (HW behavior)
    __builtin_amdgcn_global_load_lds((const __attribute__((address_space(1))) u32*)g,
                                     (__attribute__((address_space(3))) u32*)l,
                                     16, 0, 0);
}

// ---------------------------------------------------------------------------
// 256x128 tile bf16 GEMM, C = alpha*A*B^T (+bias). A: MxK (lda), B: NxK (ldb).
// BK=32, 256 threads = 4 waves (2x2), wave-tile 128x64 as 4x2 of 32x32x16.
// Rationale: LDS-port-bound model — 128^2 tile caps MfmaUtil at 64/187=34%
// (measured 31%); this tile: reads 48KB + stage-writes 24KB = 281 cyc vs
// MFMA 128 cyc -> cap 45%.
// Swizzle: logical (row r, 8-elem kchunk q) -> chunk r*4 + ((q+(r>>1))&3);
// staging permutes the GLOBAL source per lane (global_load_lds forces
// LDS offset = base + lane*16).
// VT_OUT: write C transposed into Vt[(b*1024+col)*2048 + (row&2047)]
// (b = row>>11), packed us4 — the V-projection emits V^T directly.
// ---------------------------------------------------------------------------
template<bool OUT_BF16, bool ADD_BIAS, bool VT_OUT>
__global__ __launch_bounds__(256, 2)
void gemm256(const u16* __restrict__ A, int lda, size_t strA,
             const u16* __restrict__ B, int ldb, size_t strB,
             void* __restrict__ Cv, int ldc, size_t strC,
             const float* __restrict__ bias, int K, float alpha)
{
    __shared__ __align__(16) u16 As[256 * 32];   // 16 KB
    __shared__ __align__(16) u16 Bs[128 * 32];   //  8 KB

    const int tid  = threadIdx.x;
    const int w    = tid >> 6;
    const int lane = tid & 63;
    const int wm   = w >> 1, wn = w & 1;
    const int m0   = blockIdx.y * 256, n0 = blockIdx.x * 128;
    const int l31  = lane & 31, lh = lane >> 5;

    A += (size_t)blockIdx.z * strA;
    B += (size_t)blockIdx.z * strB;

    // staging: decode chunk ids -> global source offsets
    size_t goffA[4], goffB[2];
#pragma unroll
    for (int h = 0; h < 4; ++h) {
        const int c = h * 256 + w * 64 + lane;
        const int r = c >> 2;
        const int q = ((c & 3) - (r >> 1)) & 3;
        goffA[h] = (size_t)(m0 + r) * lda + q * 8;
    }
#pragma unroll
    for (int h = 0; h < 2; ++h) {
        const int c = h * 256 + w * 64 + lane;
        const int r = c >> 2;
        const int q = ((c & 3) - (r >> 1)) & 3;
        goffB[h] = (size_t)(n0 + r) * ldb + q * 8;
    }

    // fragment LDS byte offsets (loop-invariant)
    int offA[4][2], offB[2][2];
#pragma unroll
    for (int i = 0; i < 4; ++i) {
        const int ra = wm * 128 + i * 32 + l31;
#pragma unroll
        for (int ks = 0; ks < 2; ++ks)
            offA[i][ks] = (ra * 4 + ((ks * 2 + lh + (ra >> 1)) & 3)) * 16;
    }
#pragma unroll
    for (int j = 0; j < 2; ++j) {
        const int rb = wn * 64 + j * 32 + l31;
#pragma unroll
        for (int ks = 0; ks < 2; ++ks)
            offB[j][ks] = (rb * 4 + ((ks * 2 + lh + (rb >> 1)) & 3)) * 16;
    }

    f32x16 acc[4][2] = {};

    for (int k0 = 0; k0 < K; k0 += 32) {
#pragma unroll
        for (int h = 0; h < 4; ++h)
            gload_lds16(A + goffA[h] + k0, (char*)As + (h * 256 + w * 64) * 16);
#pragma unroll
        for (int h = 0; h < 2; ++h)
            gload_lds16(B + goffB[h] + k0, (char*)Bs + (h * 256 + w * 64) * 16);
        __syncthreads();

        bf16x8 af[4][2], bfr[2][2];
#pragma unroll
        for (int i = 0; i < 4; ++i)
#pragma unroll
            for (int ks = 0; ks < 2; ++ks)
                af[i][ks] = *(const bf16x8*)((const char*)As + offA[i][ks]);
#pragma unroll
        for (int j = 0; j < 2; ++j)
#pragma unroll
            for (int ks = 0; ks < 2; ++ks)
                bfr[j][ks] = *(const bf16x8*)((const char*)Bs + offB[j][ks]);

#pragma unroll
        for (int ks = 0; ks < 2; ++ks)
#pragma unroll
            for (int i = 0; i < 4; ++i)
#pragma unroll
                for (int j = 0; j < 2; ++j)
                    acc[i][j] = __builtin_amdgcn_mfma_f32_32x32x16_bf16(
                        af[i][ks], bfr[j][ks], acc[i][j], 0, 0, 0);
        __syncthreads();
    }

    // epilogue: C/D layout col=lane&31, row=(reg&3)+8*(reg>>2)+4*(lane>>5)
    float bval[2];
    if (ADD_BIAS) {
#pragma unroll
        for (int j = 0; j < 2; ++j) bval[j] = bias[n0 + wn * 64 + j * 32 + l31];
    }
#pragma unroll
    for (int i = 0; i < 4; ++i) {
        const int rowb = m0 + wm * 128 + i * 32 + 4 * lh;
#pragma unroll
        for (int j = 0; j < 2; ++j) {
            const int col = n0 + wn * 64 + j * 32 + l31;
            if (VT_OUT) {
                // V^T output: batch from row, hardcoded S=2048, D=1024
                const int b = rowb >> 11;
                u16* dst = (u16*)Cv + ((size_t)(b * 1024) + col) * 2048 + (rowb & 2047);
#pragma unroll
                for (int g = 0; g < 4; ++g) {
                    us4 o = { f2bf(acc[i][j][4 * g + 0] + bval[j]),
                              f2bf(acc[i][j][4 * g + 1] + bval[j]),
                              f2bf(acc[i][j][4 * g + 2] + bval[j]),
                              f2bf(acc[i][j][4 * g + 3] + bval[j]) };
                    *(us4*)(dst + 8 * g) = o;
                }
            } else {
#pragma unroll
                for (int r = 0; r < 16; ++r) {
                    const int row = rowb + (r & 3) + 8 * (r >> 2);
                    float v = acc[i][j][r] * alpha;
                    if (ADD_BIAS) v += bval[j];
                    if (OUT_BF16)
                        ((u16*)Cv)[(size_t)blockIdx.z * strC + (size_t)row * ldc + col] = f2bf(v);
                    else
                        ((float*)Cv)[(size_t)blockIdx.z * strC + (size_t)row * ldc + col] = v;
                }
            }
        }
    }
}

// ---------------------------------------------------------------------------
// 128x128 tile variant (round-2 kernel, proven) — used for PV where N=1024
// makes the 256-tile grid too small (256 blocks = 1/CU).
// ---------------------------------------------------------------------------
template<bool OUT_BF16, bool ADD_BIAS>
__global__ __launch_bounds__(256)
void gemm128(const u16* __restrict__ A, int lda, size_t strA,
             const u16* __restrict__ B, int ldb, size_t strB,
             void* __restrict__ Cv, int ldc, size_t strC,
             const float* __restrict__ bias, int K, float alpha)
{
    __shared__ __align__(16) u16 As[128 * 32];
    __shared__ __align__(16) u16 Bs[128 * 32];

    const int tid  = threadIdx.x;
    const int w    = tid >> 6;
    const int lane = tid & 63;
    const int wm   = w >> 1, wn = w & 1;
    const int m0   = blockIdx.y * 128, n0 = blockIdx.x * 128;
    const int l31  = lane & 31, lh = lane >> 5;

    A += (size_t)blockIdx.z * strA;
    B += (size_t)blockIdx.z * strB;

    size_t goffA[2], goffB[2];
#pragma unroll
    for (int h = 0; h < 2; ++h) {
        const int c = h * 256 + w * 64 + lane;
        const int r = c >> 2;
        const int q = ((c & 3) - (r >> 1)) & 3;
        goffA[h] = (size_t)(m0 + r) * lda + q * 8;
        goffB[h] = (size_t)(n0 + r) * ldb + q * 8;
    }

    int offA[2][2], offB[2][2];
#pragma unroll
    for (int i = 0; i < 2; ++i) {
        const int ra = wm * 64 + i * 32 + l31;
        const int rb = wn * 64 + i * 32 + l31;
#pragma unroll
        for (int ks = 0; ks < 2; ++ks) {
            const int qq = ks * 2 + lh;
            offA[i][ks] = (ra * 4 + ((qq + (ra >> 1)) & 3)) * 16;
            offB[i][ks] = (rb * 4 + ((qq + (rb >> 1)) & 3)) * 16;
        }
    }

    f32x16 acc[2][2] = {};

    for (int k0 = 0; k0 < K; k0 += 32) {
        gload_lds16(A + goffA[0] + k0, (char*)As + (w * 64) * 16);
        gload_lds16(A + goffA[1] + k0, (char*)As + (256 + w * 64) * 16);
        gload_lds16(B + goffB[0] + k0, (char*)Bs + (w * 64) * 16);
        gload_lds16(B + goffB[1] + k0, (char*)Bs + (256 + w * 64) * 16);
        __syncthreads();

        bf16x8 af[2][2], bfr[2][2];
#pragma unroll
        for (int i = 0; i < 2; ++i)
#pragma unroll
            for (int ks = 0; ks < 2; ++ks) {
                af[i][ks]  = *(const bf16x8*)((const char*)As + offA[i][ks]);
                bfr[i][ks] = *(const bf16x8*)((const char*)Bs + offB[i][ks]);
            }
#pragma unroll
        for (int ks = 0; ks < 2; ++ks)
#pragma unroll
            for (int i = 0; i < 2; ++i)
#pragma unroll
                for (int j = 0; j < 2; ++j)
                    acc[i][j] = __builtin_amdgcn_mfma_f32_32x32x16_bf16(
                        af[i][ks], bfr[j][ks], acc[i][j], 0, 0, 0);
        __syncthreads();
    }

    float bval[2];
    if (ADD_BIAS) {
#pragma unroll
        for (int j = 0; j < 2; ++j) bval[j] = bias[n0 + wn * 64 + j * 32 + l31];
    }
#pragma unroll
    for (int i = 0; i < 2; ++i) {
        const int rowb = m0 + wm * 64 + i * 32 + 4 * lh;
#pragma unroll
        for (int j = 0; j < 2; ++j) {
            const int col = n0 + wn * 64 + j * 32 + l31;
#pragma unroll
            for (int r = 0; r < 16; ++r) {
                const int row = rowb + (r & 3) + 8 * (r >> 2);
                float v = acc[i][j][r] * alpha;
                if (ADD_BIAS) v += bval[j];
                if (OUT_BF16)
                    ((u16*)Cv)[(size_t)blockIdx.z * strC + (size_t)row * ldc + col] = f2bf(v);
                else
                    ((float*)Cv)[(size_t)blockIdx.z * strC + (size_t)row * ldc + col] = v;
            }
        }
    }
}

// X fp32 -> bf16, flat
__global__ __launch_bounds__(256)
void convert_x(const float* __restrict__ X, u16* __restrict__ Xb, int n4)
{
    int i = blockIdx.x * blockDim.x + threadIdx.x;
    if (i < n4) {
        float4 v = ((const float4*)X)[i];
        us4 o = { f2bf(v.x), f2bf(v.y), f2bf(v.z), f2bf(v.w) };
        ((us4*)Xb)[i] = o;
    }
}

// W (1024 x 3072 fp32) -> Wt (3072 x 1024 bf16)
__global__ __launch_bounds__(256)
void transpose_w(const float* __restrict__ W, u16* __restrict__ Wt)
{
    __shared__ u16 t[64][65];
    const int k0 = blockIdx.x * 64, n0 = blockIdx.y * 64;
    const int tx = threadIdx.x, ty = threadIdx.y;
#pragma unroll
    for (int i = 0; i < 64; i += 4)
        t[ty + i][tx] = f2bf(W[(size_t)(k0 + ty + i) * 3072 + n0 + tx]);
    __syncthreads();
#pragma unroll
    for (int i = 0; i < 64; i += 4)
        Wt[(size_t)(n0 + ty + i) * 1024 + k0 + tx] = t[tx][ty + i];
}

// Row softmax over 2048 bf16 logits, in place (row stride 2048 u16).
__global__ __launch_bounds__(256)
void softmax_rows(u16* __restrict__ S)
{
    __shared__ float redm[4], reds[4];
    u16* sr = S + (size_t)blockIdx.x * 2048;
    const int t = threadIdx.x;

    uint4 raw = ((const uint4*)sr)[t];                  // 8 bf16
    float x[8];
    x[0] = bf2f_lo(raw.x); x[1] = bf2f_hi(raw.x);
    x[2] = bf2f_lo(raw.y); x[3] = bf2f_hi(raw.y);
    x[4] = bf2f_lo(raw.z); x[5] = bf2f_hi(raw.z);
    x[6] = bf2f_lo(raw.w); x[7] = bf2f_hi(raw.w);

    float mx = fmaxf(fmaxf(fmaxf(x[0], x[1]), fmaxf(x[2], x[3])),
                     fmaxf(fmaxf(x[4], x[5]), fmaxf(x[6], x[7])));
#pragma unroll
    for (int o = 32; o; o >>= 1) mx = fmaxf(mx, __shfl_xor(mx, o));
    if ((t & 63) == 0) redm[t >> 6] = mx;
    __syncthreads();
    mx = fmaxf(fmaxf(redm[0], redm[1]), fmaxf(redm[2], redm[3]));

    float e[8], s = 0.f;
#pragma unroll
    for (int k = 0; k < 8; ++k) { e[k] = __expf(x[k] - mx); s += e[k]; }
#pragma unroll
    for (int o = 32; o; o >>= 1) s += __shfl_xor(s, o);
    if ((t & 63) == 0) reds[t >> 6] = s;
    __syncthreads();
    s = reds[0] + reds[1] + reds[2] + reds[3];
    const float inv = 1.0f / s;

    uint4 o4;
    o4.x = (u32)f2bf(e[0] * inv) | ((u32)f2bf(e[1] * inv) << 16);
    o4.y = (u32)f2bf(e[2] * inv) | ((u32)f2bf(e[3] * inv) << 16);
    o4.z = (u32)f2bf(e[4] * inv) | ((u32)f2bf(e[5] * inv) << 16);
    o4.w = (u32)f2bf(e[6] * inv) | ((u32)f2bf(e[7] * inv) << 16);
    ((uint4*)sr)[t] = o4;   // safe: all reads of this row happened pre-barrier
}

extern "C" void kernel_launch(void* const* d_in, const int* in_sizes, int n_in,
                              void* d_out, int out_size, void* d_ws, size_t ws_size,
                              hipStream_t stream)
{
    const float* X    = (const float*)d_in[0];   // (4,2048,1024)
    const float* W    = (const float*)d_in[1];   // (1024,3072)
    const float* bias = (const float*)d_in[2];   // (3072,)
    float* out = (float*)d_out;                  // (4,2048,1024) fp32
    char* ws = (char*)d_ws;

    // ws layout:
    //   [0,        33554432)  QK  bf16 (8192 x 2048): Q cols 0..1023, K 1024..2047
    //   [33554432, 50331648)  Vt  bf16 (4 x 1024 x 2048)
    //   [50331648, 83886080)  S/P bf16 (4 x 2048 x 2048), softmax in place
    //   Xb/Wt alias S (dead before S is written):
    //   [50331648, 67108864)  Xb  bf16 (8192 x 1024)
    //   [67108864, 73400320)  Wt  bf16 (3072 x 1024)
    u16* QK = (u16*)ws;
    u16* Vt = (u16*)(ws + 33554432);
    u16* S  = (u16*)(ws + 50331648);
    u16* Xb = (u16*)(ws + 50331648);
    u16* Wt = (u16*)(ws + 67108864);

    // 1) fp32 -> bf16 conversions
    convert_x<<<8192, 256, 0, stream>>>(X, Xb, 8192 * 1024 / 4);
    transpose_w<<<dim3(16, 48), dim3(64, 4), 0, stream>>>(W, Wt);

    // 2a) QK = Xb @ Wt[0:2048]^T + b  -> bf16 (M=8192, N=2048, K=1024)
    gemm256<true, true, false><<<dim3(16, 32, 1), 256, 0, stream>>>(
        Xb, 1024, 0, Wt, 1024, 0, QK, 2048, 0, bias, 1024, 1.0f);

    // 2b) Vt = (Xb @ Wt[2048:3072]^T + b)^T directly (M=8192, N=1024, K=1024)
    gemm256<true, true, true><<<dim3(8, 32, 1), 256, 0, stream>>>(
        Xb, 1024, 0, Wt + (size_t)2048 * 1024, 1024, 0, Vt, 2048, 0,
        bias + 2048, 1024, 1.0f);

    // 3) S[b] = (1/32) * Q[b] @ K[b]^T -> bf16 logits (M=N=2048, K=1024)
    gemm256<true, false, false><<<dim3(16, 8, 4), 256, 0, stream>>>(
        QK,        2048, (size_t)2048 * 2048,
        QK + 1024, 2048, (size_t)2048 * 2048,
        S,         2048, (size_t)2048 * 2048,
        nullptr, 1024, 0.03125f);

    // 4) row softmax in place (bf16 -> bf16 P)
    softmax_rows<<<8192, 256, 0, stream>>>(S);

    // 5) out[b] = P[b] @ Vt[b]^T  (M=2048, N=1024, K=2048), fp32 out
    gemm128<false, false><<<dim3(8, 16, 4), 256, 0, stream>>>(
        S,  2048, (size_t)2048 * 2048,
        Vt, 2048, (size_t)1024 * 2048,
        out, 1024, (size_t)2048 * 1024,
        nullptr, 2048, 1.0f);
}

// Round 4
// 273.692 us; speedup vs baseline: 1.1352x; 1.0487x over previous
//
#include <hip/hip_runtime.h>

typedef unsigned short u16;
typedef unsigned int   u32;
typedef __attribute__((ext_vector_type(8)))  short bf16x8;   // 8 bf16 = 4 VGPRs
typedef __attribute__((ext_vector_type(16))) float f32x16;
typedef __attribute__((ext_vector_type(4)))  unsigned short us4;

__device__ __forceinline__ u16 f2bf(float f) {
    union { float f; u32 u; } v; v.f = f;
    u32 u = v.u;
    return (u16)((u + 0x7fffu + ((u >> 16) & 1u)) >> 16);   // RNE
}
__device__ __forceinline__ float bf2f_lo(u32 p) {
    union { u32 u; float f; } t; t.u = p << 16; return t.f;
}
__device__ __forceinline__ float bf2f_hi(u32 p) {
    union { u32 u; float f; } t; t.u = p & 0xffff0000u; return t.f;
}

__device__ __forceinline__ void gload_lds16(const void* g, void* l) {
    // LDS dest = wave-uniform base + lane*16 (HW behavior)
    __builtin_amdgcn_global_load_lds((const __attribute__((address_space(1))) u32*)g,
                                     (__attribute__((address_space(3))) u32*)l,
                                     16, 0, 0);
}

// ---------------------------------------------------------------------------
// XCD-aware block-id decode (empirical: linear block id % 8 -> XCD).
// MODE 0 (projection, no batch): m = 8*(j&3)+x (M-blocks mult of 32... here
//        32), n = j>>2.  Per-XCD round: 4 A-blocks + 8 B-blocks ~= 4MB L2.
// MODE 2 (scores, batched, M-blocks=8): b = x>>1, m = 2*(j&3)+(x&1),
//        n = j>>2.  Each XCD serves one batch; round = 2MB Q + 2MB K.
// ---------------------------------------------------------------------------

// ---------------------------------------------------------------------------
// 256x128 tile bf16 GEMM, C = alpha*A*B^T (+bias). A: MxK (lda), B: NxK (ldb).
// BK=32, 256 threads = 4 waves (2x2), wave-tile 128x64 as 4x2 of 32x32x16.
// LDS-port model: reads 48KB + stage-writes 24KB = 281 cyc vs MFMA 128 cyc
// -> MfmaUtil cap ~45%.
// Swizzle: logical (row r, 8-elem kchunk q) -> chunk r*4 + ((q+(r>>1))&3);
// staging permutes the GLOBAL source per lane (global_load_lds forces
// LDS offset = base + lane*16).
// VT_OUT: write C transposed into Vt[(b*1024+col)*2048 + (row&2047)]
// (b = row>>11), packed us4 — the V-projection emits V^T directly.
// ---------------------------------------------------------------------------
template<bool OUT_BF16, bool ADD_BIAS, bool VT_OUT, int MODE>
__global__ __launch_bounds__(256, 2)
void gemm256(const u16* __restrict__ A, int lda, size_t strA,
             const u16* __restrict__ B, int ldb, size_t strB,
             void* __restrict__ Cv, int ldc, size_t strC,
             const float* __restrict__ bias, int K, float alpha)
{
    __shared__ __align__(16) u16 As[256 * 32];   // 16 KB
    __shared__ __align__(16) u16 Bs[128 * 32];   //  8 KB

    const int tid  = threadIdx.x;
    const int w    = tid >> 6;
    const int lane = tid & 63;
    const int wm   = w >> 1, wn = w & 1;
    const int l31  = lane & 31, lh = lane >> 5;

    // XCD-aware decode
    const u32 id = blockIdx.x;
    const u32 x  = id & 7, j = id >> 3;
    int mb, nb, bb;
    if (MODE == 0) { bb = 0;      mb = 8 * (j & 3) + x;       nb = j >> 2; }
    else           { bb = x >> 1; mb = 2 * (j & 3) + (x & 1); nb = j >> 2; }
    const int m0 = mb * 256, n0 = nb * 128;

    A += (size_t)bb * strA;
    B += (size_t)bb * strB;

    // staging: decode chunk ids -> global source offsets
    size_t goffA[4], goffB[2];
#pragma unroll
    for (int h = 0; h < 4; ++h) {
        const int c = h * 256 + w * 64 + lane;
        const int r = c >> 2;
        const int q = ((c & 3) - (r >> 1)) & 3;
        goffA[h] = (size_t)(m0 + r) * lda + q * 8;
    }
#pragma unroll
    for (int h = 0; h < 2; ++h) {
        const int c = h * 256 + w * 64 + lane;
        const int r = c >> 2;
        const int q = ((c & 3) - (r >> 1)) & 3;
        goffB[h] = (size_t)(n0 + r) * ldb + q * 8;
    }

    // fragment LDS byte offsets (loop-invariant)
    int offA[4][2], offB[2][2];
#pragma unroll
    for (int i = 0; i < 4; ++i) {
        const int ra = wm * 128 + i * 32 + l31;
#pragma unroll
        for (int ks = 0; ks < 2; ++ks)
            offA[i][ks] = (ra * 4 + ((ks * 2 + lh + (ra >> 1)) & 3)) * 16;
    }
#pragma unroll
    for (int jj = 0; jj < 2; ++jj) {
        const int rb = wn * 64 + jj * 32 + l31;
#pragma unroll
        for (int ks = 0; ks < 2; ++ks)
            offB[jj][ks] = (rb * 4 + ((ks * 2 + lh + (rb >> 1)) & 3)) * 16;
    }

    f32x16 acc[4][2] = {};

    for (int k0 = 0; k0 < K; k0 += 32) {
#pragma unroll
        for (int h = 0; h < 4; ++h)
            gload_lds16(A + goffA[h] + k0, (char*)As + (h * 256 + w * 64) * 16);
#pragma unroll
        for (int h = 0; h < 2; ++h)
            gload_lds16(B + goffB[h] + k0, (char*)Bs + (h * 256 + w * 64) * 16);
        __syncthreads();

        bf16x8 af[4][2], bfr[2][2];
#pragma unroll
        for (int i = 0; i < 4; ++i)
#pragma unroll
            for (int ks = 0; ks < 2; ++ks)
                af[i][ks] = *(const bf16x8*)((const char*)As + offA[i][ks]);
#pragma unroll
        for (int jj = 0; jj < 2; ++jj)
#pragma unroll
            for (int ks = 0; ks < 2; ++ks)
                bfr[jj][ks] = *(const bf16x8*)((const char*)Bs + offB[jj][ks]);

#pragma unroll
        for (int ks = 0; ks < 2; ++ks)
#pragma unroll
            for (int i = 0; i < 4; ++i)
#pragma unroll
                for (int jj = 0; jj < 2; ++jj)
                    acc[i][jj] = __builtin_amdgcn_mfma_f32_32x32x16_bf16(
                        af[i][ks], bfr[jj][ks], acc[i][jj], 0, 0, 0);
        __syncthreads();
    }

    // epilogue: C/D layout col=lane&31, row=(reg&3)+8*(reg>>2)+4*(lane>>5)
    float bval[2];
    if (ADD_BIAS) {
#pragma unroll
        for (int jj = 0; jj < 2; ++jj) bval[jj] = bias[n0 + wn * 64 + jj * 32 + l31];
    }
#pragma unroll
    for (int i = 0; i < 4; ++i) {
        const int rowb = m0 + wm * 128 + i * 32 + 4 * lh;
#pragma unroll
        for (int jj = 0; jj < 2; ++jj) {
            const int col = n0 + wn * 64 + jj * 32 + l31;
            if (VT_OUT) {
                // V^T output: batch from row, hardcoded S=2048, D=1024
                const int b = rowb >> 11;
                u16* dst = (u16*)Cv + ((size_t)(b * 1024) + col) * 2048 + (rowb & 2047);
#pragma unroll
                for (int g = 0; g < 4; ++g) {
                    us4 o = { f2bf(acc[i][jj][4 * g + 0] + bval[jj]),
                              f2bf(acc[i][jj][4 * g + 1] + bval[jj]),
                              f2bf(acc[i][jj][4 * g + 2] + bval[jj]),
                              f2bf(acc[i][jj][4 * g + 3] + bval[jj]) };
                    *(us4*)(dst + 8 * g) = o;
                }
            } else {
#pragma unroll
                for (int r = 0; r < 16; ++r) {
                    const int row = rowb + (r & 3) + 8 * (r >> 2);
                    float v = acc[i][jj][r] * alpha;
                    if (ADD_BIAS) v += bval[jj];
                    if (OUT_BF16)
                        ((u16*)Cv)[(size_t)bb * strC + (size_t)row * ldc + col] = f2bf(v);
                    else
                        ((float*)Cv)[(size_t)bb * strC + (size_t)row * ldc + col] = v;
                }
            }
        }
    }
}

// ---------------------------------------------------------------------------
// 128x128 tile variant — PV only (M-blocks=16, N-blocks=8, B=4, 512 blocks).
// XCD decode: b = x>>1, m = 2*(j&7)+(x&1), n = j>>3 — all 4 co-resident
// n-blocks of a row-block share its 512KB P-lines in that XCD's L2.
// ---------------------------------------------------------------------------
template<bool OUT_BF16>
__global__ __launch_bounds__(256)
void gemm128(const u16* __restrict__ A, int lda, size_t strA,
             const u16* __restrict__ B, int ldb, size_t strB,
             void* __restrict__ Cv, int ldc, size_t strC,
             int K, float alpha)
{
    __shared__ __align__(16) u16 As[128 * 32];
    __shared__ __align__(16) u16 Bs[128 * 32];

    const int tid  = threadIdx.x;
    const int w    = tid >> 6;
    const int lane = tid & 63;
    const int wm   = w >> 1, wn = w & 1;
    const int l31  = lane & 31, lh = lane >> 5;

    const u32 id = blockIdx.x;
    const u32 x  = id & 7, j = id >> 3;
    const int bb = x >> 1;
    const int mb = 2 * (int)(j & 7) + (int)(x & 1);
    const int nb = j >> 3;
    const int m0 = mb * 128, n0 = nb * 128;

    A += (size_t)bb * strA;
    B += (size_t)bb * strB;

    size_t goffA[2], goffB[2];
#pragma unroll
    for (int h = 0; h < 2; ++h) {
        const int c = h * 256 + w * 64 + lane;
        const int r = c >> 2;
        const int q = ((c & 3) - (r >> 1)) & 3;
        goffA[h] = (size_t)(m0 + r) * lda + q * 8;
        goffB[h] = (size_t)(n0 + r) * ldb + q * 8;
    }

    int offA[2][2], offB[2][2];
#pragma unroll
    for (int i = 0; i < 2; ++i) {
        const int ra = wm * 64 + i * 32 + l31;
        const int rb = wn * 64 + i * 32 + l31;
#pragma unroll
        for (int ks = 0; ks < 2; ++ks) {
            const int qq = ks * 2 + lh;
            offA[i][ks] = (ra * 4 + ((qq + (ra >> 1)) & 3)) * 16;
            offB[i][ks] = (rb * 4 + ((qq + (rb >> 1)) & 3)) * 16;
        }
    }

    f32x16 acc[2][2] = {};

    for (int k0 = 0; k0 < K; k0 += 32) {
        gload_lds16(A + goffA[0] + k0, (char*)As + (w * 64) * 16);
        gload_lds16(A + goffA[1] + k0, (char*)As + (256 + w * 64) * 16);
        gload_lds16(B + goffB[0] + k0, (char*)Bs + (w * 64) * 16);
        gload_lds16(B + goffB[1] + k0, (char*)Bs + (256 + w * 64) * 16);
        __syncthreads();

        bf16x8 af[2][2], bfr[2][2];
#pragma unroll
        for (int i = 0; i < 2; ++i)
#pragma unroll
            for (int ks = 0; ks < 2; ++ks) {
                af[i][ks]  = *(const bf16x8*)((const char*)As + offA[i][ks]);
                bfr[i][ks] = *(const bf16x8*)((const char*)Bs + offB[i][ks]);
            }
#pragma unroll
        for (int ks = 0; ks < 2; ++ks)
#pragma unroll
            for (int i = 0; i < 2; ++i)
#pragma unroll
                for (int jj = 0; jj < 2; ++jj)
                    acc[i][jj] = __builtin_amdgcn_mfma_f32_32x32x16_bf16(
                        af[i][ks], bfr[jj][ks], acc[i][jj], 0, 0, 0);
        __syncthreads();
    }

#pragma unroll
    for (int i = 0; i < 2; ++i) {
        const int rowb = m0 + wm * 64 + i * 32 + 4 * lh;
#pragma unroll
        for (int jj = 0; jj < 2; ++jj) {
            const int col = n0 + wn * 64 + jj * 32 + l31;
#pragma unroll
            for (int r = 0; r < 16; ++r) {
                const int row = rowb + (r & 3) + 8 * (r >> 2);
                float v = acc[i][jj][r] * alpha;
                if (OUT_BF16)
                    ((u16*)Cv)[(size_t)bb * strC + (size_t)row * ldc + col] = f2bf(v);
                else
                    ((float*)Cv)[(size_t)bb * strC + (size_t)row * ldc + col] = v;
            }
        }
    }
}

// X fp32 -> bf16, flat
__global__ __launch_bounds__(256)
void convert_x(const float* __restrict__ X, u16* __restrict__ Xb, int n4)
{
    int i = blockIdx.x * blockDim.x + threadIdx.x;
    if (i < n4) {
        float4 v = ((const float4*)X)[i];
        us4 o = { f2bf(v.x), f2bf(v.y), f2bf(v.z), f2bf(v.w) };
        ((us4*)Xb)[i] = o;
    }
}

// W (1024 x 3072 fp32) -> Wt (3072 x 1024 bf16)
__global__ __launch_bounds__(256)
void transpose_w(const float* __restrict__ W, u16* __restrict__ Wt)
{
    __shared__ u16 t[64][65];
    const int k0 = blockIdx.x * 64, n0 = blockIdx.y * 64;
    const int tx = threadIdx.x, ty = threadIdx.y;
#pragma unroll
    for (int i = 0; i < 64; i += 4)
        t[ty + i][tx] = f2bf(W[(size_t)(k0 + ty + i) * 3072 + n0 + tx]);
    __syncthreads();
#pragma unroll
    for (int i = 0; i < 64; i += 4)
        Wt[(size_t)(n0 + ty + i) * 1024 + k0 + tx] = t[tx][ty + i];
}

// Row softmax over 2048 bf16 logits, in place (row stride 2048 u16).
__global__ __launch_bounds__(256)
void softmax_rows(u16* __restrict__ S)
{
    __shared__ float redm[4], reds[4];
    u16* sr = S + (size_t)blockIdx.x * 2048;
    const int t = threadIdx.x;

    uint4 raw = ((const uint4*)sr)[t];                  // 8 bf16
    float xx[8];
    xx[0] = bf2f_lo(raw.x); xx[1] = bf2f_hi(raw.x);
    xx[2] = bf2f_lo(raw.y); xx[3] = bf2f_hi(raw.y);
    xx[4] = bf2f_lo(raw.z); xx[5] = bf2f_hi(raw.z);
    xx[6] = bf2f_lo(raw.w); xx[7] = bf2f_hi(raw.w);

    float mx = fmaxf(fmaxf(fmaxf(xx[0], xx[1]), fmaxf(xx[2], xx[3])),
                     fmaxf(fmaxf(xx[4], xx[5]), fmaxf(xx[6], xx[7])));
#pragma unroll
    for (int o = 32; o; o >>= 1) mx = fmaxf(mx, __shfl_xor(mx, o));
    if ((t & 63) == 0) redm[t >> 6] = mx;
    __syncthreads();
    mx = fmaxf(fmaxf(redm[0], redm[1]), fmaxf(redm[2], redm[3]));

    float e[8], s = 0.f;
#pragma unroll
    for (int k = 0; k < 8; ++k) { e[k] = __expf(xx[k] - mx); s += e[k]; }
#pragma unroll
    for (int o = 32; o; o >>= 1) s += __shfl_xor(s, o);
    if ((t & 63) == 0) reds[t >> 6] = s;
    __syncthreads();
    s = reds[0] + reds[1] + reds[2] + reds[3];
    const float inv = 1.0f / s;

    uint4 o4;
    o4.x = (u32)f2bf(e[0] * inv) | ((u32)f2bf(e[1] * inv) << 16);
    o4.y = (u32)f2bf(e[2] * inv) | ((u32)f2bf(e[3] * inv) << 16);
    o4.z = (u32)f2bf(e[4] * inv) | ((u32)f2bf(e[5] * inv) << 16);
    o4.w = (u32)f2bf(e[6] * inv) | ((u32)f2bf(e[7] * inv) << 16);
    ((uint4*)sr)[t] = o4;   // safe: all reads of this row happened pre-barrier
}

extern "C" void kernel_launch(void* const* d_in, const int* in_sizes, int n_in,
                              void* d_out, int out_size, void* d_ws, size_t ws_size,
                              hipStream_t stream)
{
    const float* X    = (const float*)d_in[0];   // (4,2048,1024)
    const float* W    = (const float*)d_in[1];   // (1024,3072)
    const float* bias = (const float*)d_in[2];   // (3072,)
    float* out = (float*)d_out;                  // (4,2048,1024) fp32
    char* ws = (char*)d_ws;

    // ws layout:
    //   [0,        33554432)  QK  bf16 (8192 x 2048): Q cols 0..1023, K 1024..2047
    //   [33554432, 50331648)  Vt  bf16 (4 x 1024 x 2048)
    //   [50331648, 83886080)  S/P bf16 (4 x 2048 x 2048), softmax in place
    //   Xb/Wt alias S (dead before S is written):
    //   [50331648, 67108864)  Xb  bf16 (8192 x 1024)
    //   [67108864, 73400320)  Wt  bf16 (3072 x 1024)
    u16* QK = (u16*)ws;
    u16* Vt = (u16*)(ws + 33554432);
    u16* S  = (u16*)(ws + 50331648);
    u16* Xb = (u16*)(ws + 50331648);
    u16* Wt = (u16*)(ws + 67108864);

    // 1) fp32 -> bf16 conversions
    convert_x<<<8192, 256, 0, stream>>>(X, Xb, 8192 * 1024 / 4);
    transpose_w<<<dim3(16, 48), dim3(64, 4), 0, stream>>>(W, Wt);

    // 2a) QK = Xb @ Wt[0:2048]^T + b  (M=8192, N=2048, K=1024), MODE 0
    gemm256<true, true, false, 0><<<512, 256, 0, stream>>>(
        Xb, 1024, 0, Wt, 1024, 0, QK, 2048, 0, bias, 1024, 1.0f);

    // 2b) Vt = (Xb @ Wt[2048:3072]^T + b)^T directly (M=8192, N=1024), MODE 0
    gemm256<true, true, true, 0><<<256, 256, 0, stream>>>(
        Xb, 1024, 0, Wt + (size_t)2048 * 1024, 1024, 0, Vt, 2048, 0,
        bias + 2048, 1024, 1.0f);

    // 3) S[b] = (1/32) * Q[b] @ K[b]^T -> bf16 logits (M=N=2048), MODE 2
    gemm256<true, false, false, 2><<<512, 256, 0, stream>>>(
        QK,        2048, (size_t)2048 * 2048,
        QK + 1024, 2048, (size_t)2048 * 2048,
        S,         2048, (size_t)2048 * 2048,
        nullptr, 1024, 0.03125f);

    // 4) row softmax in place (bf16 -> bf16 P)
    softmax_rows<<<8192, 256, 0, stream>>>(S);

    // 5) out[b] = P[b] @ Vt[b]^T  (M=2048, N=1024, K=2048), fp32 out
    gemm128<false><<<512, 256, 0, stream>>>(
        S,  2048, (size_t)2048 * 2048,
        Vt, 2048, (size_t)1024 * 2048,
        out, 1024, (size_t)2048 * 1024,
        2048, 1.0f);
}